// Round 6
// baseline (13702.577 us; speedup 1.0000x reference)
//
#include <hip/hip_runtime.h>
#include <hip/hip_bf16.h>
#include <math.h>

typedef short bf16x8 __attribute__((ext_vector_type(8)));
typedef float f32x4 __attribute__((ext_vector_type(4)));
typedef unsigned short u16;

#define NT 64
#define NB 512
#define NS 256
#define NA 64
#define NBEL 1024

// d_out element offsets (f32 elements)
#define OUT_B      0
#define OUT_SPRI   33554432
#define OUT_MUPRI  41943040
#define OUT_STDPRI 50331648
#define OUT_SPOS   58720256
#define OUT_MUPOS  67108864
#define OUT_STDPOS 75497472

__device__ __forceinline__ f32x4 mfma16(bf16x8 a, bf16x8 b, f32x4 c) {
  return __builtin_amdgcn_mfma_f32_16x16x32_bf16(a, b, c, 0, 0, 0);
}

__device__ __forceinline__ u16 f2bf(float f) {
  union { float f; unsigned u; } v; v.f = f;
  return (u16)((v.u + 0x7FFFu + ((v.u >> 16) & 1u)) >> 16);
}

__device__ __forceinline__ bf16x8 ld8bf(const u16* p) { return *(const bf16x8*)p; }

__device__ __forceinline__ bf16x8 cvt8(const float* p) {
  const float4 lo = *(const float4*)p;
  const float4 hi = *(const float4*)(p + 4);
  bf16x8 v;
  v[0] = (short)f2bf(lo.x); v[1] = (short)f2bf(lo.y);
  v[2] = (short)f2bf(lo.z); v[3] = (short)f2bf(lo.w);
  v[4] = (short)f2bf(hi.x); v[5] = (short)f2bf(hi.y);
  v[6] = (short)f2bf(hi.z); v[7] = (short)f2bf(hi.w);
  return v;
}

__device__ __forceinline__ float sigm(float x) { return 1.f / (1.f + __expf(-x)); }
__device__ __forceinline__ float softplus_(float x) {
  if (x > 20.f) return x;
  return log1pf(__expf(x));
}

#define ZACC(acc) { acc[0][0] = (f32x4){0.f,0.f,0.f,0.f}; acc[0][1] = (f32x4){0.f,0.f,0.f,0.f}; \
                    acc[1][0] = (f32x4){0.f,0.f,0.f,0.f}; acc[1][1] = (f32x4){0.f,0.f,0.f,0.f}; }

#define Q4(acc, a0v, a1v, b0v, b1v) \
  acc[0][0] = mfma16(a0v, b0v, acc[0][0]); \
  acc[0][1] = mfma16(a0v, b1v, acc[0][1]); \
  acc[1][0] = mfma16(a1v, b0v, acc[1][0]); \
  acc[1][1] = mfma16(a1v, b1v, acc[1][1]);

// K-split combine helpers through a float* LDS region.
__device__ __forceinline__ void red_write(float* L, f32x4 (&acc)[2][2], int l) {
  const int base = l * 16;
#pragma unroll
  for (int i = 0; i < 2; ++i)
#pragma unroll
    for (int j = 0; j < 2; ++j)
#pragma unroll
      for (int q = 0; q < 4; ++q)
        L[base + (i * 2 + j) * 4 + q] = acc[i][j][q];
}
__device__ __forceinline__ void red_add(const float* L, f32x4 (&acc)[2][2], int l) {
  const int base = l * 16;
#pragma unroll
  for (int i = 0; i < 2; ++i)
#pragma unroll
    for (int j = 0; j < 2; ++j)
#pragma unroll
      for (int q = 0; q < 4; ++q)
        acc[i][j][q] += L[base + (i * 2 + j) * 4 + q];
}

// swizzled LDS byte offset for x tile [64][1024] bf16 (conflict-free b128 reads)
__device__ __forceinline__ int xls_off(int row, int col) {
  return ((row * NBEL + col) * 2) ^ ((row & 7) << 4);
}

// -------- P0: weights f32 -> bf16 --------
__global__ __launch_bounds__(256) void cvt_weights_k(
    const float* __restrict__ wsa, const float* __restrict__ wih,
    const float* __restrict__ whh, const float* __restrict__ wbpri,
    const float* __restrict__ wspri, const float* __restrict__ wbpos,
    const float* __restrict__ wspos, u16* __restrict__ dst) {
  const int S0 = 327680;
  const int S1 = S0 + 3145728;
  const int S2 = S1 + 3145728;
  const int S3 = S2 + 1048576;
  const int S4 = S3 + 524288;
  const int S5 = S4 + 2097152;
  const int S6 = S5 + 524288;
  for (int i = blockIdx.x * blockDim.x + threadIdx.x; i < S6;
       i += gridDim.x * blockDim.x) {
    float v;
    if (i < S0) v = wsa[i];
    else if (i < S1) v = wih[i - S0];
    else if (i < S2) v = whh[i - S1];
    else if (i < S3) v = wbpri[i - S2];
    else if (i < S4) v = wspri[i - S3];
    else if (i < S5) v = wbpos[i - S4];
    else v = wspos[i - S5];
    dst[i] = f2bf(v);
  }
}

// -------- P1: init carries --------
__global__ __launch_bounds__(256) void init_carry_k(
    const float* __restrict__ s0, const float* __restrict__ b0,
    const float* __restrict__ Mptr, u16* __restrict__ smask,
    u16* __restrict__ bbf0, float* __restrict__ hf) {
  for (int i = blockIdx.x * blockDim.x + threadIdx.x; i < NB * NBEL;
       i += gridDim.x * blockDim.x) {
    float b = b0[i];
    bbf0[i] = f2bf(b);
    hf[i] = b;
    if (i < NB * NS) {
      int row = i >> 8;
      smask[i] = f2bf(s0[i] * Mptr[row]);
    }
  }
}

// ============ device pieces reused across kernels ============

// gh tile [64 x 128] at block index g in (8 rowgroups x 24 colgroups)
__device__ __forceinline__ void dev_gh128(
    int g, int wid8, int r16, int kq,
    const u16* __restrict__ bsrc, const u16* __restrict__ whh,
    const float* __restrict__ bhh, float* __restrict__ gh) {
  const int bm = g / 24, bn = g % 24;
  const int row0 = bm * 64 + (wid8 >> 2) * 32;
  const int col0 = bn * 128 + (wid8 & 3) * 32;
  f32x4 acc[2][2]; ZACC(acc);
  const u16* A0 = bsrc + (row0 + r16) * NBEL + kq * 8;
  const u16* A1 = A0 + 16 * NBEL;
  const u16* B0 = whh + (size_t)(col0 + r16) * NBEL + kq * 8;
  const u16* B1 = B0 + 16 * NBEL;
#pragma unroll 4
  for (int k = 0; k < NBEL; k += 32) {
    bf16x8 a0 = ld8bf(A0 + k), a1 = ld8bf(A1 + k);
    bf16x8 b0 = ld8bf(B0 + k), b1 = ld8bf(B1 + k);
    Q4(acc, a0, a1, b0, b1);
  }
#pragma unroll
  for (int i = 0; i < 2; ++i)
#pragma unroll
    for (int j = 0; j < 2; ++j)
#pragma unroll
      for (int q = 0; q < 4; ++q) {
        const int row = row0 + i * 16 + kq * 4 + q;
        const int col = col0 + j * 16 + r16;
        gh[row * 3072 + col] = acc[i][j][q] + bhh[col];
      }
}

// hbO tile (K-split 8-wave): g in (8 rowgroups x 16 colgroups), step tt
__device__ __forceinline__ void dev_hbO(
    int g, int wid, int kh, int r16, int kq, int l, int tt,
    const float* __restrict__ Of, const u16* __restrict__ wbpos,
    float* __restrict__ hbO, float* lred) {
  const int bm = g >> 4, bn = g & 15;
  const int row0 = bm * 64 + (wid >> 1) * 32;
  const int col0 = bn * 64 + (wid & 1) * 32;
  f32x4 acc[2][2]; ZACC(acc);
  const float* F0 = Of + (size_t)tt * (NB * NBEL) + (row0 + r16) * NBEL + kh * 512 + kq * 8;
  const float* F1 = F0 + 16 * NBEL;
  const u16* B0 = wbpos + (size_t)(col0 + r16) * 2048 + 1024 + kh * 512 + kq * 8;
  const u16* B1 = B0 + 16 * 2048;
#pragma unroll 4
  for (int k = 0; k < 512; k += 32) {
    bf16x8 a0 = cvt8(F0 + k), a1 = cvt8(F1 + k);
    bf16x8 b0 = ld8bf(B0 + k), b1 = ld8bf(B1 + k);
    Q4(acc, a0, a1, b0, b1);
  }
  if (kh == 1) red_write(lred, acc, l);
  __syncthreads();
  if (kh == 0) {
    red_add(lred, acc, l);
#pragma unroll
    for (int i = 0; i < 2; ++i)
#pragma unroll
      for (int j = 0; j < 2; ++j)
#pragma unroll
        for (int q = 0; q < 4; ++q) {
          const int row = row0 + i * 16 + kq * 4 + q;
          const int col = col0 + j * 16 + r16;
          hbO[row * NBEL + col] = acc[i][j][q];
        }
  }
}

// ============ kPre: gh(0) [0..191] | hbO(0) [192..319] ============
__global__ __launch_bounds__(512, 2) void kPre(
    const u16* __restrict__ bbf0, const u16* __restrict__ whh,
    const float* __restrict__ bhh, float* __restrict__ gh,
    const float* __restrict__ Of, const u16* __restrict__ wbpos,
    float* __restrict__ hbO0) {
  __shared__ float lred[4][3][1024];
  const int l = threadIdx.x & 63, r16 = l & 15, kq = l >> 4;
  const int wid8 = threadIdx.x >> 6;
  const int wid = wid8 & 3, kh = wid8 >> 2;
  if (blockIdx.x < 192) {
    dev_gh128(blockIdx.x, wid8, r16, kq, bbf0, whh, bhh, gh);
  } else {
    dev_hbO(blockIdx.x - 192, wid, kh, r16, kq, l, 0, Of, wbpos, hbO0,
            &lred[wid][0][0]);
  }
}

// ============ kB2: GRUx(t) [0..127] | bpri(t-1) [128..255] ============
// GRUx block (bm,bn): phase X: all 8 waves build x[64][1024] (rows bm*64..)
// into swizzled LDS; phase G: K-split gi (3 gates) from LDS-x, combine with
// precomputed gh (global f32) -> bnew.
__global__ __launch_bounds__(512, 2) void kB2(
    const u16* __restrict__ smask, const float* __restrict__ Af,
    const u16* __restrict__ wsa, const float* __restrict__ bsa,
    const u16* __restrict__ wih, const float* __restrict__ bih,
    const float* __restrict__ gh, float* __restrict__ hf,
    const u16* __restrict__ bprev, u16* __restrict__ bcur,
    float* __restrict__ out,
    const u16* __restrict__ wbpri, const float* __restrict__ bbpri,
    u16* __restrict__ hpri, int t) {
  __shared__ __align__(16) char smem[131072];  // x[64][1024] bf16 / lred alias
  const int l = threadIdx.x & 63, r16 = l & 15, kq = l >> 4;
  const int wid8 = threadIdx.x >> 6;
  const int wid = wid8 & 3, kh = wid8 >> 2;
  if (blockIdx.x < 128) {
    if (t >= NT) return;
    const int g = blockIdx.x, bm = g >> 4, bn = g & 15;
    // ---- phase X: x rows bm*64..bm*64+63, all 1024 cols ----
    for (int task = wid8; task < 16; task += 8) {
      const int lr0 = (task & 1) * 32;          // local row 0/32
      const int c0t = (task >> 1) * 128;        // col base 0..896
      const int grow = bm * 64 + lr0;
      for (int jt = 0; jt < 4; ++jt) {
        const int col = c0t + jt * 32;
        f32x4 acc[2][2]; ZACC(acc);
        const u16* A0 = smask + (grow + r16) * NS + kq * 8;
        const u16* A1 = A0 + 16 * NS;
        const u16* B0 = wsa + (size_t)(col + r16) * 320 + kq * 8;
        const u16* B1 = B0 + 16 * 320;
#pragma unroll
        for (int k = 0; k < 256; k += 32) {
          bf16x8 a0 = ld8bf(A0 + k), a1 = ld8bf(A1 + k);
          bf16x8 b0 = ld8bf(B0 + k), b1 = ld8bf(B1 + k);
          Q4(acc, a0, a1, b0, b1);
        }
        const float* F0 = Af + (size_t)t * (NB * NA) + (grow + r16) * NA + kq * 8;
        const float* F1 = F0 + 16 * NA;
        const u16* C0 = wsa + (size_t)(col + r16) * 320 + 256 + kq * 8;
        const u16* C1 = C0 + 16 * 320;
#pragma unroll
        for (int k = 0; k < 64; k += 32) {
          bf16x8 a0 = cvt8(F0 + k), a1 = cvt8(F1 + k);
          bf16x8 b0 = ld8bf(C0 + k), b1 = ld8bf(C1 + k);
          Q4(acc, a0, a1, b0, b1);
        }
#pragma unroll
        for (int i = 0; i < 2; ++i)
#pragma unroll
          for (int j = 0; j < 2; ++j)
#pragma unroll
            for (int q = 0; q < 4; ++q) {
              const int lr = lr0 + i * 16 + kq * 4 + q;
              const int c = col + j * 16 + r16;
              const u16 v = f2bf(fmaxf(acc[i][j][q] + bsa[c], 0.f));
              *(u16*)(smem + xls_off(lr, c)) = v;
            }
      }
    }
    __syncthreads();
    // ---- phase G: gi (3 gates), K-split 512/512, A from LDS-x ----
    const int lrow0 = (wid >> 1) * 32;
    const int grow0 = bm * 64 + lrow0;
    const int col0 = bn * 64 + (wid & 1) * 32;
    f32x4 ar[2][2], az[2][2], an[2][2];
    ZACC(ar); ZACC(az); ZACC(an);
    const u16* Br0 = wih + (size_t)(col0 + r16) * NBEL + kh * 512 + kq * 8;
    const u16* Br1 = Br0 + 16 * NBEL;
    const u16* Bz0 = wih + (size_t)(col0 + 1024 + r16) * NBEL + kh * 512 + kq * 8;
    const u16* Bz1 = Bz0 + 16 * NBEL;
    const u16* Bn0 = wih + (size_t)(col0 + 2048 + r16) * NBEL + kh * 512 + kq * 8;
    const u16* Bn1 = Bn0 + 16 * NBEL;
#pragma unroll 4
    for (int k = 0; k < 512; k += 32) {
      const int ks = kh * 512 + k + kq * 8;
      bf16x8 a0 = *(const bf16x8*)(smem + xls_off(lrow0 + r16, ks));
      bf16x8 a1 = *(const bf16x8*)(smem + xls_off(lrow0 + 16 + r16, ks));
      bf16x8 b0 = ld8bf(Br0 + k), b1 = ld8bf(Br1 + k);
      Q4(ar, a0, a1, b0, b1);
      bf16x8 c0 = ld8bf(Bz0 + k), c1 = ld8bf(Bz1 + k);
      Q4(az, a0, a1, c0, c1);
      bf16x8 d0 = ld8bf(Bn0 + k), d1 = ld8bf(Bn1 + k);
      Q4(an, a0, a1, d0, d1);
    }
    __syncthreads();  // everyone done reading x before lred alias write
    float (*lred)[3][1024] = (float (*)[3][1024])smem;
    if (kh == 1) {
      red_write(&lred[wid][0][0], ar, l);
      red_write(&lred[wid][1][0], az, l);
      red_write(&lred[wid][2][0], an, l);
    }
    __syncthreads();
    if (kh == 0) {
      const int base = l * 16;
#pragma unroll
      for (int i = 0; i < 2; ++i)
#pragma unroll
        for (int j = 0; j < 2; ++j)
#pragma unroll
          for (int q = 0; q < 4; ++q) {
            const int row = grow0 + i * 16 + kq * 4 + q;
            const int c = col0 + j * 16 + r16;
            const int li = base + (i * 2 + j) * 4 + q;
            const float* ghrow = gh + row * 3072;
            const float r = sigm(ar[i][j][q] + lred[wid][0][li] + bih[c] + ghrow[c]);
            const float z = sigm(az[i][j][q] + lred[wid][1][li] + bih[c + 1024] + ghrow[c + 1024]);
            const float n = tanhf(an[i][j][q] + lred[wid][2][li] + bih[c + 2048] +
                                  r * ghrow[c + 2048]);
            const float h = hf[row * NBEL + c];
            const float bnew = (1.f - z) * n + z * h;
            hf[row * NBEL + c] = bnew;
            bcur[row * NBEL + c] = f2bf(bnew);
            out[OUT_B + (size_t)t * (NB * NBEL) + row * NBEL + c] = bnew;
          }
    }
  } else {
    // bpri(t-1): hpri = relu(bprev @ Wbpri^T + b), K-split
    if (t < 1) return;
    float (*lred)[3][1024] = (float (*)[3][1024])smem;
    const int g = blockIdx.x - 128, bm = g >> 4, bn = g & 15;
    const int row0 = bm * 64 + (wid >> 1) * 32;
    const int col0 = bn * 64 + (wid & 1) * 32;
    f32x4 acc[2][2]; ZACC(acc);
    const u16* A0 = bprev + (row0 + r16) * NBEL + kh * 512 + kq * 8;
    const u16* A1 = A0 + 16 * NBEL;
    const u16* B0 = wbpri + (size_t)(col0 + r16) * NBEL + kh * 512 + kq * 8;
    const u16* B1 = B0 + 16 * NBEL;
#pragma unroll 4
    for (int k = 0; k < 512; k += 32) {
      bf16x8 a0 = ld8bf(A0 + k), a1 = ld8bf(A1 + k);
      bf16x8 b0 = ld8bf(B0 + k), b1 = ld8bf(B1 + k);
      Q4(acc, a0, a1, b0, b1);
    }
    if (kh == 1) red_write(&lred[wid][0][0], acc, l);
    __syncthreads();
    if (kh == 0) {
      red_add(&lred[wid][0][0], acc, l);
#pragma unroll
      for (int i = 0; i < 2; ++i)
#pragma unroll
        for (int j = 0; j < 2; ++j)
#pragma unroll
          for (int q = 0; q < 4; ++q) {
            const int row = row0 + i * 16 + kq * 4 + q;
            const int col = col0 + j * 16 + r16;
            hpri[row * NBEL + col] = f2bf(fmaxf(acc[i][j][q] + bbpri[col], 0.f));
          }
    }
  }
}

// ============ kC2: hbB(t)[0..127] | gh(t+1)[128..319] | hbO(t+1)[320..447] | spri(t-1)[448..479] ============
__global__ __launch_bounds__(512, 2) void kC2(
    const u16* __restrict__ bcur, const u16* __restrict__ wbpos,
    const float* __restrict__ bbpos, const float* __restrict__ hbOc,
    u16* __restrict__ hbbf,
    const u16* __restrict__ whh, const float* __restrict__ bhh,
    float* __restrict__ gh,
    const float* __restrict__ Of, float* __restrict__ hbOn,
    const u16* __restrict__ hpri, const u16* __restrict__ wspri,
    const float* __restrict__ bspri, const float* __restrict__ npri,
    float* __restrict__ out, int t) {
  __shared__ float lred[4][3][1024];
  const int l = threadIdx.x & 63, r16 = l & 15, kq = l >> 4;
  const int wid8 = threadIdx.x >> 6;
  const int wid = wid8 & 3, kh = wid8 >> 2;
  if (blockIdx.x < 128) {
    if (t >= NT) return;
    const int g = blockIdx.x, bm = g >> 4, bn = g & 15;
    const int row0 = bm * 64 + (wid >> 1) * 32;
    const int col0 = bn * 64 + (wid & 1) * 32;
    f32x4 acc[2][2]; ZACC(acc);
    const u16* A0 = bcur + (row0 + r16) * NBEL + kh * 512 + kq * 8;
    const u16* A1 = A0 + 16 * NBEL;
    const u16* B0 = wbpos + (size_t)(col0 + r16) * 2048 + kh * 512 + kq * 8;
    const u16* B1 = B0 + 16 * 2048;
#pragma unroll 4
    for (int k = 0; k < 512; k += 32) {
      bf16x8 a0 = ld8bf(A0 + k), a1 = ld8bf(A1 + k);
      bf16x8 b0 = ld8bf(B0 + k), b1 = ld8bf(B1 + k);
      Q4(acc, a0, a1, b0, b1);
    }
    if (kh == 1) red_write(&lred[wid][0][0], acc, l);
    __syncthreads();
    if (kh == 0) {
      red_add(&lred[wid][0][0], acc, l);
#pragma unroll
      for (int i = 0; i < 2; ++i)
#pragma unroll
        for (int j = 0; j < 2; ++j)
#pragma unroll
          for (int q = 0; q < 4; ++q) {
            const int row = row0 + i * 16 + kq * 4 + q;
            const int col = col0 + j * 16 + r16;
            const float v = acc[i][j][q] + hbOc[row * NBEL + col] + bbpos[col];
            hbbf[row * NBEL + col] = f2bf(fmaxf(v, 0.f));
          }
    }
  } else if (blockIdx.x < 320) {
    if (t + 1 >= NT) return;
    dev_gh128(blockIdx.x - 128, wid8, r16, kq, bcur, whh, bhh, gh);
  } else if (blockIdx.x < 448) {
    if (t + 1 >= NT) return;
    dev_hbO(blockIdx.x - 320, wid, kh, r16, kq, l, t + 1, Of, wbpos, hbOn,
            &lred[wid][0][0]);
  } else {
    if (t < 1) return;
    const int g = blockIdx.x - 448, bm = g >> 2, bn = g & 3;
    const int row0 = bm * 64 + (wid >> 1) * 32;
    const int c0 = bn * 64 + (wid & 1) * 32;
    f32x4 am[2][2], ah[2][2];
    ZACC(am); ZACC(ah);
    const u16* A0 = hpri + (row0 + r16) * NBEL + kh * 512 + kq * 8;
    const u16* A1 = A0 + 16 * NBEL;
    const u16* Bm0 = wspri + (size_t)(c0 + r16) * NBEL + kh * 512 + kq * 8;
    const u16* Bm1 = Bm0 + 16 * NBEL;
    const u16* Bh0 = wspri + (size_t)(c0 + 256 + r16) * NBEL + kh * 512 + kq * 8;
    const u16* Bh1 = Bh0 + 16 * NBEL;
#pragma unroll 4
    for (int k = 0; k < 512; k += 32) {
      bf16x8 a0 = ld8bf(A0 + k), a1 = ld8bf(A1 + k);
      bf16x8 m0 = ld8bf(Bm0 + k), m1 = ld8bf(Bm1 + k);
      Q4(am, a0, a1, m0, m1);
      bf16x8 h0 = ld8bf(Bh0 + k), h1 = ld8bf(Bh1 + k);
      Q4(ah, a0, a1, h0, h1);
    }
    if (kh == 1) {
      red_write(&lred[wid][0][0], am, l);
      red_write(&lred[wid][1][0], ah, l);
    }
    __syncthreads();
    if (kh == 0) {
      red_add(&lred[wid][0][0], am, l);
      red_add(&lred[wid][1][0], ah, l);
      const int tt = t - 1;
#pragma unroll
      for (int i = 0; i < 2; ++i)
#pragma unroll
        for (int j = 0; j < 2; ++j)
#pragma unroll
          for (int q = 0; q < 4; ++q) {
            const int row = row0 + i * 16 + kq * 4 + q;
            const int c = c0 + j * 16 + r16;
            const size_t idx = (size_t)tt * (NB * NS) + row * NS + c;
            const float mu = am[i][j][q] + bspri[c];
            const float hp = ah[i][j][q] + bspri[c + 256];
            const float sd = softplus_(hp) + 0.1f;
            out[OUT_SPRI + idx] = mu + sd * npri[idx];
            out[OUT_MUPRI + idx] = mu;
            out[OUT_STDPRI + idx] = sd;
          }
    }
  }
}

// ============ kD: spos(t) [32 blocks] ============
__global__ __launch_bounds__(512, 2) void kD(
    const u16* __restrict__ hbbf, const u16* __restrict__ wspos,
    const float* __restrict__ bspos, const float* __restrict__ npos,
    const float* __restrict__ Mptr, float* __restrict__ out,
    u16* __restrict__ smask, int t) {
  __shared__ float lred[4][2][1024];
  const int l = threadIdx.x & 63, r16 = l & 15, kq = l >> 4;
  const int wid8 = threadIdx.x >> 6;
  const int wid = wid8 & 3, kh = wid8 >> 2;
  const int g = blockIdx.x, bm = g >> 2, bn = g & 3;
  const int row0 = bm * 64 + (wid >> 1) * 32;
  const int c0 = bn * 64 + (wid & 1) * 32;
  f32x4 am[2][2], ah[2][2];
  ZACC(am); ZACC(ah);
  const u16* A0 = hbbf + (row0 + r16) * NBEL + kh * 512 + kq * 8;
  const u16* A1 = A0 + 16 * NBEL;
  const u16* Bm0 = wspos + (size_t)(c0 + r16) * NBEL + kh * 512 + kq * 8;
  const u16* Bm1 = Bm0 + 16 * NBEL;
  const u16* Bh0 = wspos + (size_t)(c0 + 256 + r16) * NBEL + kh * 512 + kq * 8;
  const u16* Bh1 = Bh0 + 16 * NBEL;
#pragma unroll 4
  for (int k = 0; k < 512; k += 32) {
    bf16x8 a0 = ld8bf(A0 + k), a1 = ld8bf(A1 + k);
    bf16x8 m0 = ld8bf(Bm0 + k), m1 = ld8bf(Bm1 + k);
    Q4(am, a0, a1, m0, m1);
    bf16x8 h0 = ld8bf(Bh0 + k), h1 = ld8bf(Bh1 + k);
    Q4(ah, a0, a1, h0, h1);
  }
  if (kh == 1) {
    red_write(&lred[wid][0][0], am, l);
    red_write(&lred[wid][1][0], ah, l);
  }
  __syncthreads();
  if (kh == 0) {
    red_add(&lred[wid][0][0], am, l);
    red_add(&lred[wid][1][0], ah, l);
#pragma unroll
    for (int i = 0; i < 2; ++i)
#pragma unroll
      for (int j = 0; j < 2; ++j)
#pragma unroll
        for (int q = 0; q < 4; ++q) {
          const int row = row0 + i * 16 + kq * 4 + q;
          const int c = c0 + j * 16 + r16;
          const float mu = am[i][j][q] + bspos[c];
          const float hq = ah[i][j][q] + bspos[c + 256];
          const float sd = softplus_(hq) + 0.1f;
          const size_t idx = (size_t)t * (NB * NS) + row * NS + c;
          const float sq = mu + sd * npos[idx];
          out[OUT_SPOS + idx] = sq;
          out[OUT_MUPOS + idx] = mu;
          out[OUT_STDPOS + idx] = sd;
          const float mn = (t < NT - 1) ? Mptr[(t + 1) * NB + row] : 1.f;
          smask[row * NS + c] = f2bf(sq * mn);
        }
  }
}

extern "C" void kernel_launch(void* const* d_in, const int* in_sizes, int n_in,
                              void* d_out, int out_size, void* d_ws, size_t ws_size,
                              hipStream_t stream) {
  const float* s0 = (const float*)d_in[0];
  const float* Af = (const float*)d_in[1];
  const float* b0 = (const float*)d_in[2];
  const float* Of = (const float*)d_in[3];
  const float* Mp = (const float*)d_in[4];
  const float* npri = (const float*)d_in[5];
  const float* npos = (const float*)d_in[6];
  const float* Wsa = (const float*)d_in[7];
  const float* bsa = (const float*)d_in[8];
  const float* Wih = (const float*)d_in[9];
  const float* bih = (const float*)d_in[10];
  const float* Whh = (const float*)d_in[11];
  const float* bhh = (const float*)d_in[12];
  const float* Wbpri = (const float*)d_in[13];
  const float* bbpri = (const float*)d_in[14];
  const float* Wspri = (const float*)d_in[15];
  const float* bspri = (const float*)d_in[16];
  const float* Wbpos = (const float*)d_in[17];
  const float* bbpos = (const float*)d_in[18];
  const float* Wspos = (const float*)d_in[19];
  const float* bspos = (const float*)d_in[20];

  float* out = (float*)d_out;
  char* ws = (char*)d_ws;
  u16* wbase   = (u16*)ws;
  u16* wsa_b   = wbase;
  u16* wih_b   = wbase + 327680;
  u16* whh_b   = wbase + 3473408;
  u16* wbpri_b = wbase + 6619136;
  u16* wspri_b = wbase + 7667712;
  u16* wbpos_b = wbase + 8192000;
  u16* wspos_b = wbase + 10289152;
  // weights end at byte 21,626,880
  u16*   smask = (u16*)  (ws + 21626880);  // [512,256]  bf16
  u16*   bbf0  = (u16*)  (ws + 21889024);  // [512,1024] bf16
  u16*   bbf1  = (u16*)  (ws + 22937600);  // [512,1024] bf16
  float* hf    = (float*)(ws + 23986176);  // [512,1024] f32
  float* gh    = (float*)(ws + 26083328);  // [512,3072] f32 6MB
  float* hbO0  = (float*)(ws + 32374784);  // [512,1024] f32
  float* hbO1  = (float*)(ws + 34471936);  // [512,1024] f32
  u16*   hbbf  = (u16*)  (ws + 36569088);  // [512,1024] bf16
  u16*   hpri  = (u16*)  (ws + 37617664);  // [512,1024] bf16
  // ws end: 38,666,240 bytes

  cvt_weights_k<<<2048, 256, 0, stream>>>(Wsa, Wih, Whh, Wbpri, Wspri, Wbpos,
                                          Wspos, wbase);
  init_carry_k<<<2048, 256, 0, stream>>>(s0, b0, Mp, smask, bbf0, hf);
  kPre<<<320, 512, 0, stream>>>(bbf0, whh_b, bhh, gh, Of, wbpos_b, hbO0);

  for (int t = 0; t < NT; ++t) {
    const u16* bprev = (t & 1) ? bbf1 : bbf0;
    u16* bcur = (t & 1) ? bbf0 : bbf1;
    float* hbOc = (t & 1) ? hbO1 : hbO0;
    float* hbOn = (t & 1) ? hbO0 : hbO1;
    kB2<<<256, 512, 0, stream>>>(smask, Af, wsa_b, bsa, wih_b, bih, gh, hf,
                                 bprev, bcur, out, wbpri_b, bbpri, hpri, t);
    kC2<<<480, 512, 0, stream>>>(bcur, wbpos_b, bbpos, hbOc, hbbf,
                                 whh_b, bhh, gh, Of, hbOn,
                                 hpri, wspri_b, bspri, npri, out, t);
    kD<<<32, 512, 0, stream>>>(hbbf, wspos_b, bspos, npos, Mp, out, smask, t);
  }
  // tail: bpri(63) then spri(63)
  {
    const int t = NT;  // even -> bprev = bbf0 = bnew(63)
    const u16* bprev = (t & 1) ? bbf1 : bbf0;
    u16* bcur = (t & 1) ? bbf0 : bbf1;
    float* hbOc = (t & 1) ? hbO1 : hbO0;
    float* hbOn = (t & 1) ? hbO0 : hbO1;
    kB2<<<256, 512, 0, stream>>>(smask, Af, wsa_b, bsa, wih_b, bih, gh, hf,
                                 bprev, bcur, out, wbpri_b, bbpri, hpri, t);
    kC2<<<480, 512, 0, stream>>>(bcur, wbpos_b, bbpos, hbOc, hbbf,
                                 whh_b, bhh, gh, Of, hbOn,
                                 hpri, wspri_b, bspri, npri, out, t);
  }
}